// Round 3
// baseline (240.599 us; speedup 1.0000x reference)
//
#include <hip/hip_runtime.h>

// Problem constants
#define BN 32768
#define KN 5
#define LN 128
#define HN 3
#define ROWS (BN*KN)        // 163840
#define BK ROWS
#define MT 64               // rows per tile
#define TILES (ROWS/MT)     // 2560
#define WGS 256             // one WG per CU, single round
#define TPW (TILES/WGS)     // 10 tiles per workgroup
#define THREADS 1024        // 16 waves: 8 col-groups x 2 gate-halves
#define HSTR 152            // sH row stride ush: 128 h + 16 zeros (k-pad) + 8 pad
#define ESTR 24             // sEmb row stride ush: 16 + 8 pad
#define GSTR 36             // sG per-col stride f32: 32 rows + 4 pad (16B-aligned)
#define LOG2E 1.44269504089f

using bf16x8 = __attribute__((ext_vector_type(8))) __bf16;
using bf16x2 = __attribute__((ext_vector_type(2))) __bf16;
using f32x4  = __attribute__((ext_vector_type(4))) float;
using u16x8  = __attribute__((ext_vector_type(8))) unsigned short;

__device__ inline unsigned short f2bf(float x) {
    union { float f; unsigned u; } v; v.f = x;
    unsigned r = v.u + 0x7FFFu + ((v.u >> 16) & 1u);   // RNE
    return (unsigned short)(r >> 16);
}
#if __has_builtin(__builtin_amdgcn_cvt_pk_bf16_f32)
__device__ inline unsigned short f2bf_fast(float x) {
    union { bf16x2 v; unsigned short us[2]; } u;
    u.v = __builtin_amdgcn_cvt_pk_bf16_f32(x, x);
    return u.us[0];
}
#else
__device__ inline unsigned short f2bf_fast(float x) { return f2bf(x); }
#endif
__device__ inline float bf2f(unsigned short b) {
    union { unsigned u; float f; } v; v.u = ((unsigned)b) << 16; return v.f;
}
__device__ inline float sigm(float x) {
    return __builtin_amdgcn_rcpf(1.0f + __builtin_amdgcn_exp2f(-LOG2E * x));
}
__device__ inline f32x4 splat4(float x) { f32x4 r; r[0]=x; r[1]=x; r[2]=x; r[3]=x; return r; }

__global__ __launch_bounds__(THREADS, 4)   // 128-reg cap -> 4 waves/SIMD (16 waves/CU)
void wahead_kernel(const float* __restrict__ z,   const float* __restrict__ anchors,
                   const float* __restrict__ W1,  const float* __restrict__ b1,
                   const float* __restrict__ W2,  const float* __restrict__ b2,
                   const float* __restrict__ Wih, const float* __restrict__ Whh,
                   const float* __restrict__ bih, const float* __restrict__ bhh,
                   const float* __restrict__ Wp,  const float* __restrict__ bp,
                   const float* __restrict__ Wr,  const float* __restrict__ br,
                   float* __restrict__ out)
{
    // sH: ping-pong h (bf16), cols 0..127 = h, 128..143 = permanent zeros (K pad)
    __shared__ __align__(16) unsigned short sH[2 * MT * HSTR];    // 38912 B
    __shared__ __align__(16) unsigned short sEmb[MT * ESTR];      //  3072 B
    // sG: gate-pair exchange, f32 exact. [p][writer_wh][g][col 16][GSTR]
    __shared__ __align__(16) float sG[8 * 2 * 2 * 16 * GSTR];     // 73728 B
    __shared__ float sW1[32], sb1[16], sW2[16 * 17], sb2[16], sWp[128], sWr[384];

    const int tid  = threadIdx.x;
    const int wvid = tid >> 6;       // 0..15
    const int cg   = wvid & 7;       // col-group: l-cols cg*16..cg*16+15
    const int wh   = wvid >> 3;      // gate-half: 0 -> {i,f}, 1 -> {g,o}
    const int lane = tid & 63;
    const int quad = lane >> 4;
    const int cc   = lane & 15;
    const int lcol = cg * 16 + cc;   // l in [0,128)

    // ---- stage small constant weights into LDS ----
    if (tid < 32)  sW1[tid] = W1[tid];
    if (tid < 16)  { sb1[tid] = b1[tid]; sb2[tid] = b2[tid]; }
    if (tid < 256) sW2[(tid >> 4) * 17 + (tid & 15)] = W2[tid];   // sW2[col*17+hh]
    if (tid < 128) sWp[tid] = Wp[tid];
    if (tid < 384) sWr[tid] = Wr[tid];

    // ---- zero the K-pad columns (128..143) of both h buffers, once ----
    {
        const int bnum = tid >> 9;            // 0..1
        const int rr   = (tid >> 3) & 63;     // 0..63
        const int c0   = 128 + (tid & 7) * 2; // 128..142
        *reinterpret_cast<unsigned*>(&sH[bnum * MT * HSTR + rr * HSTR + c0]) = 0u;
    }

    // ---- per-wave B fragments: 2 gates x [W_ih(16)|W_hh(128)|0(16)], scales folded ----
    // gates i,f,o scaled by -log2e; gate g by +2*log2e (exp2 applies directly to acc).
    bf16x8 Bf[2][5];
    float  biasv[2];
    #pragma unroll
    for (int g = 0; g < 2; ++g) {
        const int t = wh * 2 + g;                      // absolute gate 0..3 (i,f,g,o)
        const float sc = (t == 2) ? (2.0f * LOG2E) : (-LOG2E);
        const int n = t * 128 + lcol;                  // gate output col in [0,512)
        biasv[g] = sc * (bih[n] + bhh[n]);
        #pragma unroll
        for (int kt = 0; kt < 5; ++kt) {
            const int k0 = kt * 32 + quad * 8;
            float v[8];
            if (k0 < 16) {                             // W_ih region
                const float4 p0 = *reinterpret_cast<const float4*>(Wih + n * 16 + k0);
                const float4 p1 = *reinterpret_cast<const float4*>(Wih + n * 16 + k0 + 4);
                v[0]=p0.x; v[1]=p0.y; v[2]=p0.z; v[3]=p0.w;
                v[4]=p1.x; v[5]=p1.y; v[6]=p1.z; v[7]=p1.w;
            } else if (k0 < 144) {                     // W_hh region
                const float4 p0 = *reinterpret_cast<const float4*>(Whh + n * 128 + (k0 - 16));
                const float4 p1 = *reinterpret_cast<const float4*>(Whh + n * 128 + (k0 - 16) + 4);
                v[0]=p0.x; v[1]=p0.y; v[2]=p0.z; v[3]=p0.w;
                v[4]=p1.x; v[5]=p1.y; v[6]=p1.z; v[7]=p1.w;
            } else {                                   // zero pad k in [144,160)
                #pragma unroll
                for (int j = 0; j < 8; ++j) v[j] = 0.0f;
            }
            union { bf16x8 bv; unsigned short us[8]; } pk;
            #pragma unroll
            for (int j = 0; j < 8; ++j) pk.us[j] = f2bf(sc * v[j]);
            Bf[g][kt] = pk.bv;
        }
    }

    const float bpv = bp[0];
    const float br0 = br[0], br1 = br[1], br2 = br[2];

    __syncthreads();   // consts + zero-pad staged

    const int erow = tid >> 4;   // 0..63 (16 threads per row)
    const int esub = tid & 15;   // 0..15

    #pragma unroll 1
    for (int ti = 0; ti < TPW; ++ti) {
        const int tile = blockIdx.x * TPW + ti;
        const int r0g  = tile * MT;

        // -------- staging: emb MLP (1 col/thread) + initial h = z --------
        {
            const int gr = r0g + erow;
            const float2 an = *reinterpret_cast<const float2*>(anchors + gr * 2);
            float a0 = sb2[esub];
            #pragma unroll
            for (int hh = 0; hh < 16; ++hh) {
                float pre = fmaf(sW1[hh * 2], an.x, fmaf(sW1[hh * 2 + 1], an.y, sb1[hh]));
                pre = fmaxf(pre, 0.0f);
                a0 = fmaf(pre, sW2[esub * 17 + hh], a0);
            }
            sEmb[erow * ESTR + esub] = f2bf(a0);
            // initial h = z[b] into buffer 0: 8 elems/thread
            const unsigned b_idx = (unsigned)gr / 5u;
            const float4* zp = reinterpret_cast<const float4*>(z + (size_t)b_idx * 128 + esub * 8);
            const float4 z0 = zp[0], z1 = zp[1];
            union { u16x8 v; unsigned short us[8]; } w0;
            w0.us[0]=f2bf(z0.x); w0.us[1]=f2bf(z0.y); w0.us[2]=f2bf(z0.z); w0.us[3]=f2bf(z0.w);
            w0.us[4]=f2bf(z1.x); w0.us[5]=f2bf(z1.y); w0.us[6]=f2bf(z1.z); w0.us[7]=f2bf(z1.w);
            *reinterpret_cast<u16x8*>(&sH[erow * HSTR + esub * 8]) = w0.v;
        }

        float cst[8];
        #pragma unroll
        for (int e = 0; e < 8; ++e) cst[e] = 0.0f;

        #pragma unroll
        for (int s = 0; s < HN; ++s) {
            const int cur = s & 1;
            const int nxt = cur ^ 1;
            __syncthreads();   // (1) staging / previous-step h visible

            f32x4 acc[2][2][2];   // [ownsel 0=own-half,1=shipped][mo][g]
            #pragma unroll
            for (int os = 0; os < 2; ++os)
                #pragma unroll
                for (int mo = 0; mo < 2; ++mo)
                    #pragma unroll
                    for (int g = 0; g < 2; ++g)
                        acc[os][mo][g] = splat4(biasv[g]);

            const unsigned short* sHc = &sH[cur * MT * HSTR];

            // shipped half first (os=1) so sG writes overlap own-half MFMAs
            #pragma unroll
            for (int osi = 0; osi < 2; ++osi) {
                const int os = 1 - osi;
                const int hb = os ? (wh ^ 1) : wh;     // row-half computed
                #pragma unroll
                for (int mo = 0; mo < 2; ++mo) {
                    const int arow = (hb * 2 + mo) * 16 + cc;
                    const unsigned short* hr = &sHc[arow * HSTR];
                    const unsigned short* a0p = (quad < 2)
                        ? &sEmb[arow * ESTR + quad * 8]
                        : &hr[(quad - 2) * 8];
                    const bf16x8 af0 = *reinterpret_cast<const bf16x8*>(a0p);
                    const bf16x8 af1 = *reinterpret_cast<const bf16x8*>(&hr[16  + quad * 8]);
                    const bf16x8 af2 = *reinterpret_cast<const bf16x8*>(&hr[48  + quad * 8]);
                    const bf16x8 af3 = *reinterpret_cast<const bf16x8*>(&hr[80  + quad * 8]);
                    const bf16x8 af4 = *reinterpret_cast<const bf16x8*>(&hr[112 + quad * 8]);
                    #pragma unroll
                    for (int g = 0; g < 2; ++g) {
                        acc[os][mo][g] = __builtin_amdgcn_mfma_f32_16x16x32_bf16(af0, Bf[g][0], acc[os][mo][g], 0, 0, 0);
                        acc[os][mo][g] = __builtin_amdgcn_mfma_f32_16x16x32_bf16(af1, Bf[g][1], acc[os][mo][g], 0, 0, 0);
                        acc[os][mo][g] = __builtin_amdgcn_mfma_f32_16x16x32_bf16(af2, Bf[g][2], acc[os][mo][g], 0, 0, 0);
                        acc[os][mo][g] = __builtin_amdgcn_mfma_f32_16x16x32_bf16(af3, Bf[g][3], acc[os][mo][g], 0, 0, 0);
                        acc[os][mo][g] = __builtin_amdgcn_mfma_f32_16x16x32_bf16(af4, Bf[g][4], acc[os][mo][g], 0, 0, 0);
                    }
                }
                if (os == 1) {
                    // ship other-half rows' pre-acts (f32 exact) to the pair wave
                    #pragma unroll
                    for (int mo = 0; mo < 2; ++mo)
                        #pragma unroll
                        for (int g = 0; g < 2; ++g)
                            *reinterpret_cast<f32x4*>(
                                &sG[(((cg * 2 + wh) * 2 + g) * 16 + cc) * GSTR + mo * 16 + quad * 4]) =
                                acc[1][mo][g];
                }
            }

            __syncthreads();   // (2) sG exchange visible

            // ---- pointwise: own 32 rows x 16 cols (8 elems/lane) ----
            f32x4 og[2][2];
            #pragma unroll
            for (int mo = 0; mo < 2; ++mo)
                #pragma unroll
                for (int g = 0; g < 2; ++g)
                    og[mo][g] = *reinterpret_cast<const f32x4*>(
                        &sG[(((cg * 2 + (wh ^ 1)) * 2 + g) * 16 + cc) * GSTR + mo * 16 + quad * 4]);

            unsigned short* sHn = &sH[nxt * MT * HSTR];
            #pragma unroll
            for (int mo = 0; mo < 2; ++mo) {
                // map (own pair, other pair) -> absolute gates i,f,g,o (wave-uniform select)
                const f32x4 vi = wh ? og[mo][0]     : acc[0][mo][0];
                const f32x4 vf = wh ? og[mo][1]     : acc[0][mo][1];
                const f32x4 vg = wh ? acc[0][mo][0] : og[mo][0];
                const f32x4 vo = wh ? acc[0][mo][1] : og[mo][1];
                #pragma unroll
                for (int r = 0; r < 4; ++r) {
                    const int e = mo * 4 + r;
                    const float Ei = __builtin_amdgcn_exp2f(vi[r]);   // e^-i
                    const float Ef = __builtin_amdgcn_exp2f(vf[r]);   // e^-f
                    const float Eg = __builtin_amdgcn_exp2f(vg[r]);   // e^{2g}
                    const float Eo = __builtin_amdgcn_exp2f(vo[r]);   // e^-o
                    const float t1  = (1.0f + Ei) * (1.0f + Eg);
                    const float ef1 = 1.0f + Ef;
                    const float t3  = (Eg - 1.0f) * ef1;
                    const float num = fmaf(cst[e], t1, t3);
                    const float cn  = num * __builtin_amdgcn_rcpf(t1 * ef1);
                    cst[e] = cn;
                    const float Ec = __builtin_amdgcn_exp2f(2.0f * LOG2E * cn);  // e^{2c}
                    const float hn = (Ec - 1.0f) *
                        __builtin_amdgcn_rcpf((1.0f + Eo) * (1.0f + Ec));
                    const int row = wh * 32 + mo * 16 + quad * 4 + r;
                    sHn[row * HSTR + lcol] = f2bf_fast(hn);
                }
            }
        }

        __syncthreads();   // final h (buffer 1) complete

        // -------- epilogue: heads; 16 threads/row, 8 l each --------
        {
            const int row = tid >> 4;    // 0..63
            const int j   = tid & 15;    // 0..15
            const u16x8 h0 = *reinterpret_cast<const u16x8*>(
                &sH[1 * MT * HSTR + row * HSTR + j * 8]);
            float pp = 0.f, q0 = 0.f, q1 = 0.f, q2 = 0.f;
            #pragma unroll
            for (int u = 0; u < 8; ++u) {
                const int l = j * 8 + u;
                const float hv = bf2f(h0[u]);
                pp = fmaf(hv, sWp[l], pp);
                q0 = fmaf(hv, sWr[l], q0);
                q1 = fmaf(hv, sWr[128 + l], q1);
                q2 = fmaf(hv, sWr[256 + l], q2);
            }
            #pragma unroll
            for (int m = 1; m < 16; m <<= 1) {
                pp += __shfl_xor(pp, m, 64);
                q0 += __shfl_xor(q0, m, 64);
                q1 += __shfl_xor(q1, m, 64);
                q2 += __shfl_xor(q2, m, 64);
            }
            if (j == 0) {
                const int gr = r0g + row;
                const float prog  = pp + bpv;
                const float rr0 = q0 + br0, rr1 = q1 + br1, rr2 = q2 + br2;
                const float rmean = (rr0 + rr1 + rr2) * (1.0f / 3.0f);
                const float s0 = sigm(rr0), s1 = sigm(rr1), s2 = sigm(rr2);
                const float sm = (s0 + s1 + s2) * (1.0f / 3.0f);
                const float d0 = s0 - sm, d1 = s1 - sm, d2 = s2 - sm;
                const float unc = (d0 * d0 + d1 * d1 + d2 * d2) * 0.5f;   // ddof=1
                out[gr]          = rmean;
                out[BK + gr]     = prog;
                out[2 * BK + gr] = unc;
                out[3 * BK + gr] = rr0;
                out[4 * BK + gr] = rr1;
                out[5 * BK + gr] = rr2;
            }
        }
        // next-tile staging writes sEmb + buf0 h-cols; epilogue reads buf1 —
        // disjoint; the step-0 barrier orders staging before the first MFMA.
    }
}

extern "C" void kernel_launch(void* const* d_in, const int* in_sizes, int n_in,
                              void* d_out, int out_size, void* d_ws, size_t ws_size,
                              hipStream_t stream) {
    const float* z       = (const float*)d_in[0];
    const float* anchors = (const float*)d_in[1];
    const float* W1      = (const float*)d_in[2];
    const float* b1      = (const float*)d_in[3];
    const float* W2      = (const float*)d_in[4];
    const float* b2      = (const float*)d_in[5];
    const float* Wih     = (const float*)d_in[6];
    const float* Whh     = (const float*)d_in[7];
    const float* bih     = (const float*)d_in[8];
    const float* bhh     = (const float*)d_in[9];
    const float* Wp      = (const float*)d_in[10];
    const float* bp      = (const float*)d_in[11];
    const float* Wr      = (const float*)d_in[12];
    const float* br      = (const float*)d_in[13];

    hipLaunchKernelGGL(wahead_kernel, dim3(WGS), dim3(THREADS), 0, stream,
                       z, anchors, W1, b1, W2, b2, Wih, Whh, bih, bhh,
                       Wp, bp, Wr, br, (float*)d_out);
}

// Round 4
// 216.268 us; speedup vs baseline: 1.1125x; 1.1125x over previous
//
#include <hip/hip_runtime.h>

// Problem constants
#define BN 32768
#define KN 5
#define LN 128
#define HN 3
#define ROWS (BN*KN)        // 163840
#define BK ROWS
#define MT 64               // rows per tile
#define TILES (ROWS/MT)     // 2560
#define WGS 512
#define TPW (TILES/WGS)     // 5 tiles per workgroup
#define THREADS 512         // 8 waves
#define ASTR 168            // A row stride bf16: [emb16|h128|zero16] + 8 pad
#define LOG2E 1.44269504089f

using bf16x8 = __attribute__((ext_vector_type(8))) __bf16;
using bf16x2 = __attribute__((ext_vector_type(2))) __bf16;
using f32x4  = __attribute__((ext_vector_type(4))) float;
using u16x8  = __attribute__((ext_vector_type(8))) unsigned short;

__device__ inline unsigned short f2bf(float x) {
    union { float f; unsigned u; } v; v.f = x;
    unsigned r = v.u + 0x7FFFu + ((v.u >> 16) & 1u);   // RNE
    return (unsigned short)(r >> 16);
}
#if __has_builtin(__builtin_amdgcn_cvt_pk_bf16_f32)
__device__ inline unsigned short f2bf_fast(float x) {
    union { bf16x2 v; unsigned short us[2]; } u;
    u.v = __builtin_amdgcn_cvt_pk_bf16_f32(x, x);
    return u.us[0];
}
__device__ inline unsigned pk2bf(float lo, float hi) {   // D.lo=bf16(S0), D.hi=bf16(S1)
    union { bf16x2 v; unsigned u; } q;
    q.v = __builtin_amdgcn_cvt_pk_bf16_f32(lo, hi);
    return q.u;
}
#else
__device__ inline unsigned short f2bf_fast(float x) { return f2bf(x); }
__device__ inline unsigned pk2bf(float lo, float hi) {
    return (unsigned)f2bf(lo) | ((unsigned)f2bf(hi) << 16);
}
#endif
__device__ inline float bf2f(unsigned short b) {
    union { unsigned u; float f; } v; v.u = ((unsigned)b) << 16; return v.f;
}
__device__ inline float sigm(float x) {
    return __builtin_amdgcn_rcpf(1.0f + __builtin_amdgcn_exp2f(-LOG2E * x));
}
__device__ inline f32x4 splat4(float x) { f32x4 r; r[0]=x; r[1]=x; r[2]=x; r[3]=x; return r; }

#if __has_builtin(__builtin_amdgcn_sched_group_barrier)
#define SGB(m_, n_) __builtin_amdgcn_sched_group_barrier((m_), (n_), 0)
#else
#define SGB(m_, n_)
#endif
// SchedGroupMask: VALU=0x2 (incl. trans), MFMA=0x8, DS_READ=0x100, DS_WRITE=0x200

// Pointwise LSTM nonlinearity for one m-tile (4 acc rows). WB_ = per-thread
// write base into the NEXT h buffer; offsets are compile-time immediates.
#define PW_MT(MTI, WB_) do {                                                       \
    _Pragma("unroll")                                                              \
    for (int r_ = 0; r_ < 4; ++r_) {                                               \
        const float Ei = __builtin_amdgcn_exp2f(acc[MTI][0][r_]);   /* e^-i  */    \
        const float Ef = __builtin_amdgcn_exp2f(acc[MTI][1][r_]);   /* e^-f  */    \
        const float Eg = __builtin_amdgcn_exp2f(acc[MTI][2][r_]);   /* e^{2g}*/    \
        const float Eo = __builtin_amdgcn_exp2f(acc[MTI][3][r_]);   /* e^-o  */    \
        const float t1  = (1.0f + Ei) * (1.0f + Eg);                               \
        const float ef1 = 1.0f + Ef;                                               \
        const float t3  = (Eg - 1.0f) * ef1;                                       \
        const float num = fmaf(cst[(MTI)*4 + r_], t1, t3);                         \
        const float cn  = num * __builtin_amdgcn_rcpf(t1 * ef1);                   \
        cst[(MTI)*4 + r_] = cn;                                                    \
        const float Ec = __builtin_amdgcn_exp2f(2.0f * LOG2E * cn);                \
        const float hn = (Ec - 1.0f) *                                             \
            __builtin_amdgcn_rcpf((1.0f + Eo) * (1.0f + Ec));                      \
        (WB_)[(MTI)*16*ASTR + r_*ASTR] = f2bf_fast(hn);                            \
    }                                                                              \
} while (0)

__global__ __launch_bounds__(THREADS, 2)   // 256-reg cap: no spills
void wahead_kernel(const float* __restrict__ z,   const float* __restrict__ anchors,
                   const float* __restrict__ W1,  const float* __restrict__ b1,
                   const float* __restrict__ W2,  const float* __restrict__ b2,
                   const float* __restrict__ Wih, const float* __restrict__ Whh,
                   const float* __restrict__ bih, const float* __restrict__ bhh,
                   const float* __restrict__ Wp,  const float* __restrict__ bp,
                   const float* __restrict__ Wr,  const float* __restrict__ br,
                   float* __restrict__ out)
{
    __shared__ unsigned short sA[2 * MT * ASTR];   // ping-pong [emb|h|0] bf16, 43 KB
    __shared__ float sW1[32], sb1[16], sW2[16 * 17], sb2[16], sWp[128], sWr[384];

    const int tid  = threadIdx.x;
    const int wv   = tid >> 6;       // wave 0..7: owns l-cols wv*16..wv*16+15 of each gate
    const int lane = tid & 63;
    const int quad = lane >> 4;
    const int cc   = lane & 15;
    const int lcol = wv * 16 + cc;

    // ---- stage small constant weights into LDS ----
    if (tid < 32)  sW1[tid] = W1[tid];
    if (tid < 16)  { sb1[tid] = b1[tid]; sb2[tid] = b2[tid]; }
    if (tid < 256) sW2[(tid >> 4) * 17 + (tid & 15)] = W2[tid];   // sW2[col*17+hh]
    if (tid < 128) sWp[tid] = Wp[tid];
    if (tid < 384) sWr[tid] = Wr[tid];

    // ---- stacked-B fragments [W_ih(16)|W_hh(128)|0(16)] with FOLDED gate scales ----
    bf16x8 Bf[4][5];
    float  biasv[4];
    #pragma unroll
    for (int t = 0; t < 4; ++t) {                      // gate i,f,g,o
        const float sc = (t == 2) ? (2.0f * LOG2E) : (-LOG2E);
        const int n = t * 128 + wv * 16 + cc;          // gate output col in [0,512)
        biasv[t] = sc * (bih[n] + bhh[n]);
        #pragma unroll
        for (int kt = 0; kt < 5; ++kt) {
            const int k0 = kt * 32 + quad * 8;
            float v[8];
            if (k0 < 16) {                             // W_ih region
                const float4 p0 = *reinterpret_cast<const float4*>(Wih + n * 16 + k0);
                const float4 p1 = *reinterpret_cast<const float4*>(Wih + n * 16 + k0 + 4);
                v[0]=p0.x; v[1]=p0.y; v[2]=p0.z; v[3]=p0.w;
                v[4]=p1.x; v[5]=p1.y; v[6]=p1.z; v[7]=p1.w;
            } else if (k0 < 144) {                     // W_hh region
                const float4 p0 = *reinterpret_cast<const float4*>(Whh + n * 128 + (k0 - 16));
                const float4 p1 = *reinterpret_cast<const float4*>(Whh + n * 128 + (k0 - 16) + 4);
                v[0]=p0.x; v[1]=p0.y; v[2]=p0.z; v[3]=p0.w;
                v[4]=p1.x; v[5]=p1.y; v[6]=p1.z; v[7]=p1.w;
            } else {                                   // zero pad k in [144,160)
                #pragma unroll
                for (int j = 0; j < 8; ++j) v[j] = 0.0f;
            }
            union { bf16x8 bv; unsigned short us[8]; } pk;
            #pragma unroll
            for (int j = 0; j < 8; ++j) pk.us[j] = f2bf(sc * v[j]);
            Bf[t][kt] = pk.bv;
        }
    }

    const float bpv = bp[0];
    const float br0 = br[0], br1 = br[1], br2 = br[2];

    __syncthreads();   // consts staged

    const int erow = tid >> 3;   // 0..63 (8 threads per row)
    const int esub = tid & 7;    // 0..7

    // ---- per-thread LDS base pointers (per buffer) — all step addressing
    //      becomes base + compile-time immediate (no per-access VALU) ----
    const unsigned short* rbB[2];   // A-frag read base: row cc, k-offset quad*8
    unsigned short*       wbB[2];   // h write base: row quad*4, col 16+lcol
    rbB[0] = &sA[0 * MT * ASTR + cc * ASTR + quad * 8];
    rbB[1] = &sA[1 * MT * ASTR + cc * ASTR + quad * 8];
    wbB[0] = &sA[0 * MT * ASTR + (quad * 4) * ASTR + 16 + lcol];
    wbB[1] = &sA[1 * MT * ASTR + (quad * 4) * ASTR + 16 + lcol];

    // ---- preload tile 0 inputs (anchors + z) into registers ----
    float  pax, pay;
    float4 pz0, pz1, pz2, pz3;
    {
        const int gr = blockIdx.x * TPW * MT + erow;
        const float2 an = *reinterpret_cast<const float2*>(anchors + gr * 2);
        pax = an.x; pay = an.y;
        const unsigned b_idx = (unsigned)gr / 5u;
        const float4* zp = reinterpret_cast<const float4*>(z + (size_t)b_idx * 128 + esub * 16);
        pz0 = zp[0]; pz1 = zp[1]; pz2 = zp[2]; pz3 = zp[3];
    }

    #pragma unroll 1
    for (int ti = 0; ti < TPW; ++ti) {
        const int tile = blockIdx.x * TPW + ti;
        const int r0g  = tile * MT;

        // -------- staging: emb MLP (2 cols/thread) + zero-pad + z --------
        {
            const float ax = pax, ay = pay;
            const int e0 = esub * 2;
            float a0 = sb2[e0], a1 = sb2[e0 + 1];
            #pragma unroll
            for (int hh = 0; hh < 16; ++hh) {
                float pre = fmaf(sW1[hh * 2], ax, fmaf(sW1[hh * 2 + 1], ay, sb1[hh]));
                pre = fmaxf(pre, 0.0f);
                a0 = fmaf(pre, sW2[e0 * 17 + hh], a0);
                a1 = fmaf(pre, sW2[(e0 + 1) * 17 + hh], a1);
            }
            const unsigned embp = pk2bf(a0, a1);
            #pragma unroll
            for (int bufi = 0; bufi < 2; ++bufi) {
                unsigned short* row = &sA[bufi * MT * ASTR + erow * ASTR];
                *reinterpret_cast<unsigned*>(&row[e0]) = embp;
                *reinterpret_cast<unsigned*>(&row[144 + e0]) = 0u;
            }
            // initial h = z[b] (bf16) into buffer 0, cols 16..143: 16 elems/thread
            union { u16x8 v; unsigned u32[4]; } w0, w1;
            w0.u32[0] = pk2bf(pz0.x, pz0.y); w0.u32[1] = pk2bf(pz0.z, pz0.w);
            w0.u32[2] = pk2bf(pz1.x, pz1.y); w0.u32[3] = pk2bf(pz1.z, pz1.w);
            w1.u32[0] = pk2bf(pz2.x, pz2.y); w1.u32[1] = pk2bf(pz2.z, pz2.w);
            w1.u32[2] = pk2bf(pz3.x, pz3.y); w1.u32[3] = pk2bf(pz3.z, pz3.w);
            unsigned short* hrow = &sA[erow * ASTR + 16 + esub * 16];
            *reinterpret_cast<u16x8*>(hrow)     = w0.v;
            *reinterpret_cast<u16x8*>(hrow + 8) = w1.v;
        }

        float cst[16];
        #pragma unroll
        for (int e = 0; e < 16; ++e) cst[e] = 0.0f;

        #pragma unroll
        for (int s = 0; s < HN; ++s) {
            const int cur = s & 1;          // compile-time after unroll
            const int nxt = cur ^ 1;
            __syncthreads();   // staging / previous-step h writes visible

            // next-tile global preload at start of LAST step (hides under compute)
            if (s == HN - 1 && ti + 1 < TPW) {
                const int gr = (r0g + MT) + erow;
                const float2 an = *reinterpret_cast<const float2*>(anchors + gr * 2);
                pax = an.x; pay = an.y;
                const unsigned b_idx = (unsigned)gr / 5u;
                const float4* zp = reinterpret_cast<const float4*>(z + (size_t)b_idx * 128 + esub * 16);
                pz0 = zp[0]; pz1 = zp[1]; pz2 = zp[2]; pz3 = zp[3];
            }

            const unsigned short* rb = rbB[cur];
            unsigned short*       wb = wbB[nxt];

            f32x4 acc[4][4];
            #pragma unroll
            for (int mt = 0; mt < 4; ++mt)
                #pragma unroll
                for (int t = 0; t < 4; ++t)
                    acc[mt][t] = splat4(biasv[t]);

            bf16x8 af[2][5];
            #pragma unroll
            for (int kt = 0; kt < 5; ++kt)
                af[0][kt] = *reinterpret_cast<const bf16x8*>(rb + kt * 32);

            // ---- mt0: MFMA(af0) + prefetch mt1 ----
            #pragma unroll
            for (int kt = 0; kt < 5; ++kt)
                af[1][kt] = *reinterpret_cast<const bf16x8*>(rb + 1 * 16 * ASTR + kt * 32);
            #pragma unroll
            for (int kt = 0; kt < 5; ++kt)
                #pragma unroll
                for (int t = 0; t < 4; ++t)
                    acc[0][t] = __builtin_amdgcn_mfma_f32_16x16x32_bf16(
                        af[0][kt], Bf[t][kt], acc[0][t], 0, 0, 0);
            SGB(0x100, 5);
            #pragma unroll
            for (int i_ = 0; i_ < 20; ++i_) { SGB(0x8, 1); SGB(0x2, 2); }

            // ---- mt1: MFMA(af1) + prefetch mt2 + PW(0) in MFMA shadow ----
            #pragma unroll
            for (int kt = 0; kt < 5; ++kt)
                af[0][kt] = *reinterpret_cast<const bf16x8*>(rb + 2 * 16 * ASTR + kt * 32);
            #pragma unroll
            for (int kt = 0; kt < 5; ++kt)
                #pragma unroll
                for (int t = 0; t < 4; ++t)
                    acc[1][t] = __builtin_amdgcn_mfma_f32_16x16x32_bf16(
                        af[1][kt], Bf[t][kt], acc[1][t], 0, 0, 0);
            PW_MT(0, wb);
            SGB(0x100, 5);
            #pragma unroll
            for (int i_ = 0; i_ < 20; ++i_) { SGB(0x8, 1); SGB(0x2, 5); }
            SGB(0x200, 4);

            // ---- mt2: MFMA(af0) + prefetch mt3 + PW(1) ----
            #pragma unroll
            for (int kt = 0; kt < 5; ++kt)
                af[1][kt] = *reinterpret_cast<const bf16x8*>(rb + 3 * 16 * ASTR + kt * 32);
            #pragma unroll
            for (int kt = 0; kt < 5; ++kt)
                #pragma unroll
                for (int t = 0; t < 4; ++t)
                    acc[2][t] = __builtin_amdgcn_mfma_f32_16x16x32_bf16(
                        af[0][kt], Bf[t][kt], acc[2][t], 0, 0, 0);
            PW_MT(1, wb);
            SGB(0x100, 5);
            #pragma unroll
            for (int i_ = 0; i_ < 20; ++i_) { SGB(0x8, 1); SGB(0x2, 5); }
            SGB(0x200, 4);

            // ---- mt3: MFMA(af1) + PW(2) ----
            #pragma unroll
            for (int kt = 0; kt < 5; ++kt)
                #pragma unroll
                for (int t = 0; t < 4; ++t)
                    acc[3][t] = __builtin_amdgcn_mfma_f32_16x16x32_bf16(
                        af[1][kt], Bf[t][kt], acc[3][t], 0, 0, 0);
            PW_MT(2, wb);
            #pragma unroll
            for (int i_ = 0; i_ < 20; ++i_) { SGB(0x8, 1); SGB(0x2, 5); }
            SGB(0x200, 4);

            // ---- tail: PW(3) (nothing left to overlap) ----
            PW_MT(3, wb);
        }

        __syncthreads();   // final h (buffer 1) complete

        // -------- epilogue: heads; 8 threads/row, 16 l each --------
        {
            const int row = tid >> 3;    // 0..63
            const int j   = tid & 7;     // 0..7
            const unsigned short* hrow = &sA[1 * MT * ASTR + row * ASTR + 16 + j * 16];
            const u16x8 h0 = *reinterpret_cast<const u16x8*>(hrow);
            const u16x8 h1 = *reinterpret_cast<const u16x8*>(hrow + 8);
            float p = 0.f, q0 = 0.f, q1 = 0.f, q2 = 0.f;
            #pragma unroll
            for (int u = 0; u < 16; ++u) {
                const int l = j * 16 + u;
                const float hv = bf2f(u < 8 ? h0[u] : h1[u - 8]);
                p  = fmaf(hv, sWp[l], p);
                q0 = fmaf(hv, sWr[l], q0);
                q1 = fmaf(hv, sWr[128 + l], q1);
                q2 = fmaf(hv, sWr[256 + l], q2);
            }
            #pragma unroll
            for (int m = 1; m < 8; m <<= 1) {
                p  += __shfl_xor(p,  m, 64);
                q0 += __shfl_xor(q0, m, 64);
                q1 += __shfl_xor(q1, m, 64);
                q2 += __shfl_xor(q2, m, 64);
            }
            if (j == 0) {
                const int gr = r0g + row;
                const float prog  = p + bpv;
                const float rr0 = q0 + br0, rr1 = q1 + br1, rr2 = q2 + br2;
                const float rmean = (rr0 + rr1 + rr2) * (1.0f / 3.0f);
                const float s0 = sigm(rr0), s1 = sigm(rr1), s2 = sigm(rr2);
                const float sm = (s0 + s1 + s2) * (1.0f / 3.0f);
                const float d0 = s0 - sm, d1 = s1 - sm, d2 = s2 - sm;
                const float unc = (d0 * d0 + d1 * d1 + d2 * d2) * 0.5f;   // ddof=1
                out[gr]          = rmean;
                out[BK + gr]     = prog;
                out[2 * BK + gr] = unc;
                out[3 * BK + gr] = rr0;
                out[4 * BK + gr] = rr1;
                out[5 * BK + gr] = rr2;
            }
        }
        // next-tile staging writes emb/pad cols (both bufs) + buf0 h (z);
        // epilogue reads buf1 h-cols — disjoint; step-0 barrier orders the rest.
    }
}

extern "C" void kernel_launch(void* const* d_in, const int* in_sizes, int n_in,
                              void* d_out, int out_size, void* d_ws, size_t ws_size,
                              hipStream_t stream) {
    const float* z       = (const float*)d_in[0];
    const float* anchors = (const float*)d_in[1];
    const float* W1      = (const float*)d_in[2];
    const float* b1      = (const float*)d_in[3];
    const float* W2      = (const float*)d_in[4];
    const float* b2      = (const float*)d_in[5];
    const float* Wih     = (const float*)d_in[6];
    const float* Whh     = (const float*)d_in[7];
    const float* bih     = (const float*)d_in[8];
    const float* bhh     = (const float*)d_in[9];
    const float* Wp      = (const float*)d_in[10];
    const float* bp      = (const float*)d_in[11];
    const float* Wr      = (const float*)d_in[12];
    const float* br      = (const float*)d_in[13];

    hipLaunchKernelGGL(wahead_kernel, dim3(WGS), dim3(THREADS), 0, stream,
                       z, anchors, W1, b1, W2, b2, Wih, Whh, bih, bhh,
                       Wp, bp, Wr, br, (float*)d_out);
}

// Round 5
// 195.460 us; speedup vs baseline: 1.2309x; 1.1065x over previous
//
#include <hip/hip_runtime.h>

// Problem constants
#define BN 32768
#define KN 5
#define LN 128
#define HN 3
#define ROWS (BN*KN)        // 163840
#define BK ROWS
#define MT 128              // rows per tile (doubled: amortize per-step fixed costs)
#define TILES (ROWS/MT)     // 1280
#define WGS 256             // one WG per CU, single round
#define TPW (TILES/WGS)     // 5 tiles per workgroup
#define THREADS 512         // 8 waves
#define ASTR 168            // A row stride bf16: [emb16|h128|zero16] + 8 pad
#define LOG2E 1.44269504089f

using bf16x8 = __attribute__((ext_vector_type(8))) __bf16;
using bf16x2 = __attribute__((ext_vector_type(2))) __bf16;
using f32x4  = __attribute__((ext_vector_type(4))) float;
using u16x8  = __attribute__((ext_vector_type(8))) unsigned short;

__device__ inline unsigned short f2bf(float x) {
    union { float f; unsigned u; } v; v.f = x;
    unsigned r = v.u + 0x7FFFu + ((v.u >> 16) & 1u);   // RNE
    return (unsigned short)(r >> 16);
}
#if __has_builtin(__builtin_amdgcn_cvt_pk_bf16_f32)
__device__ inline unsigned short f2bf_fast(float x) {
    union { bf16x2 v; unsigned short us[2]; } u;
    u.v = __builtin_amdgcn_cvt_pk_bf16_f32(x, x);
    return u.us[0];
}
__device__ inline unsigned pk2bf(float lo, float hi) {   // D.lo=bf16(S0), D.hi=bf16(S1)
    union { bf16x2 v; unsigned u; } q;
    q.v = __builtin_amdgcn_cvt_pk_bf16_f32(lo, hi);
    return q.u;
}
#else
__device__ inline unsigned short f2bf_fast(float x) { return f2bf(x); }
__device__ inline unsigned pk2bf(float lo, float hi) {
    return (unsigned)f2bf(lo) | ((unsigned)f2bf(hi) << 16);
}
#endif
__device__ inline float bf2f(unsigned short b) {
    union { unsigned u; float f; } v; v.u = ((unsigned)b) << 16; return v.f;
}
__device__ inline float sigm(float x) {
    return __builtin_amdgcn_rcpf(1.0f + __builtin_amdgcn_exp2f(-LOG2E * x));
}
__device__ inline f32x4 splat4(float x) { f32x4 r; r[0]=x; r[1]=x; r[2]=x; r[3]=x; return r; }

// Pointwise LSTM nonlinearity for one m-tile (4 acc rows), acc bank ACCI,
// logical m-tile MTI (0..7). WB_ = per-thread write base into next h buffer.
#define PW_MT(ACCI, MTI, WB_) do {                                                 \
    _Pragma("unroll")                                                              \
    for (int r_ = 0; r_ < 4; ++r_) {                                               \
        const float Ei = __builtin_amdgcn_exp2f(acc[ACCI][0][r_]);  /* e^-i  */    \
        const float Ef = __builtin_amdgcn_exp2f(acc[ACCI][1][r_]);  /* e^-f  */    \
        const float Eg = __builtin_amdgcn_exp2f(acc[ACCI][2][r_]);  /* e^{2g}*/    \
        const float Eo = __builtin_amdgcn_exp2f(acc[ACCI][3][r_]);  /* e^-o  */    \
        const float t1  = (1.0f + Ei) * (1.0f + Eg);                               \
        const float ef1 = 1.0f + Ef;                                               \
        const float t3  = (Eg - 1.0f) * ef1;                                       \
        const float num = fmaf(cst[(MTI)*4 + r_], t1, t3);                         \
        const float cn  = num * __builtin_amdgcn_rcpf(t1 * ef1);                   \
        cst[(MTI)*4 + r_] = cn;                                                    \
        const float Ec = __builtin_amdgcn_exp2f(2.0f * LOG2E * cn);                \
        const float hn = (Ec - 1.0f) *                                             \
            __builtin_amdgcn_rcpf((1.0f + Eo) * (1.0f + Ec));                      \
        (WB_)[(MTI)*16*ASTR + r_*ASTR] = f2bf_fast(hn);                            \
    }                                                                              \
} while (0)

__global__ __launch_bounds__(THREADS, 2)   // 256-reg cap
void wahead_kernel(const float* __restrict__ z,   const float* __restrict__ anchors,
                   const float* __restrict__ W1,  const float* __restrict__ b1,
                   const float* __restrict__ W2,  const float* __restrict__ b2,
                   const float* __restrict__ Wih, const float* __restrict__ Whh,
                   const float* __restrict__ bih, const float* __restrict__ bhh,
                   const float* __restrict__ Wp,  const float* __restrict__ bp,
                   const float* __restrict__ Wr,  const float* __restrict__ br,
                   float* __restrict__ out)
{
    __shared__ unsigned short sA[2 * MT * ASTR];   // ping-pong [emb|h|0] bf16, 86 KB
    __shared__ float sW1[32], sb1[16], sW2[16 * 17], sb2[16], sWp[128], sWr[384];

    const int tid  = threadIdx.x;
    const int wv   = tid >> 6;       // wave 0..7: owns l-cols wv*16..wv*16+15 of each gate
    const int lane = tid & 63;
    const int quad = lane >> 4;
    const int cc   = lane & 15;
    const int lcol = wv * 16 + cc;

    // ---- stage small constant weights into LDS ----
    if (tid < 32)  sW1[tid] = W1[tid];
    if (tid < 16)  { sb1[tid] = b1[tid]; sb2[tid] = b2[tid]; }
    if (tid < 256) sW2[(tid >> 4) * 17 + (tid & 15)] = W2[tid];   // sW2[col*17+hh]
    if (tid < 128) sWp[tid] = Wp[tid];
    if (tid < 384) sWr[tid] = Wr[tid];

    // ---- stacked-B fragments [W_ih(16)|W_hh(128)|0(16)] with FOLDED gate scales ----
    // gates i,f,o scaled by -log2e; gate g scaled by +2*log2e, so exp2() applies
    // directly to the MFMA accumulators.  B layout (16x16x32): n=lane&15, k=quad*8+j
    bf16x8 Bf[4][5];
    float  biasv[4];
    #pragma unroll
    for (int t = 0; t < 4; ++t) {                      // gate i,f,g,o
        const float sc = (t == 2) ? (2.0f * LOG2E) : (-LOG2E);
        const int n = t * 128 + wv * 16 + cc;          // gate output col in [0,512)
        biasv[t] = sc * (bih[n] + bhh[n]);
        #pragma unroll
        for (int kt = 0; kt < 5; ++kt) {
            const int k0 = kt * 32 + quad * 8;
            float v[8];
            if (k0 < 16) {                             // W_ih region
                const float4 p0 = *reinterpret_cast<const float4*>(Wih + n * 16 + k0);
                const float4 p1 = *reinterpret_cast<const float4*>(Wih + n * 16 + k0 + 4);
                v[0]=p0.x; v[1]=p0.y; v[2]=p0.z; v[3]=p0.w;
                v[4]=p1.x; v[5]=p1.y; v[6]=p1.z; v[7]=p1.w;
            } else if (k0 < 144) {                     // W_hh region
                const float4 p0 = *reinterpret_cast<const float4*>(Whh + n * 128 + (k0 - 16));
                const float4 p1 = *reinterpret_cast<const float4*>(Whh + n * 128 + (k0 - 16) + 4);
                v[0]=p0.x; v[1]=p0.y; v[2]=p0.z; v[3]=p0.w;
                v[4]=p1.x; v[5]=p1.y; v[6]=p1.z; v[7]=p1.w;
            } else {                                   // zero pad k in [144,160)
                #pragma unroll
                for (int j = 0; j < 8; ++j) v[j] = 0.0f;
            }
            union { bf16x8 bv; unsigned short us[8]; } pk;
            #pragma unroll
            for (int j = 0; j < 8; ++j) pk.us[j] = f2bf(sc * v[j]);
            Bf[t][kt] = pk.bv;
        }
    }

    const float bpv = bp[0];
    const float br0 = br[0], br1 = br[1], br2 = br[2];

    __syncthreads();   // consts staged

    const int erow = tid >> 2;   // 0..127 (4 threads per row)
    const int esub = tid & 3;    // 0..3

    // ---- per-thread LDS base pointers (per buffer): step addressing is
    //      base + compile-time immediate ----
    const unsigned short* rbB[2];   // A-frag read base: row cc, k-offset quad*8
    unsigned short*       wbB[2];   // h write base: row quad*4, col 16+lcol
    rbB[0] = &sA[0 * MT * ASTR + cc * ASTR + quad * 8];
    rbB[1] = &sA[1 * MT * ASTR + cc * ASTR + quad * 8];
    wbB[0] = &sA[0 * MT * ASTR + (quad * 4) * ASTR + 16 + lcol];
    wbB[1] = &sA[1 * MT * ASTR + (quad * 4) * ASTR + 16 + lcol];

    #pragma unroll 1
    for (int ti = 0; ti < TPW; ++ti) {
        const int tile = blockIdx.x * TPW + ti;
        const int r0g  = tile * MT;

        // -------- staging: emb MLP (4 cols/thread) + zero-pad + z --------
        {
            const int gr = r0g + erow;
            const float2 an = *reinterpret_cast<const float2*>(anchors + gr * 2);
            const int e0 = esub * 4;
            float a0 = sb2[e0], a1 = sb2[e0 + 1], a2 = sb2[e0 + 2], a3 = sb2[e0 + 3];
            #pragma unroll
            for (int hh = 0; hh < 16; ++hh) {
                float pre = fmaf(sW1[hh * 2], an.x, fmaf(sW1[hh * 2 + 1], an.y, sb1[hh]));
                pre = fmaxf(pre, 0.0f);
                a0 = fmaf(pre, sW2[e0 * 17 + hh], a0);
                a1 = fmaf(pre, sW2[(e0 + 1) * 17 + hh], a1);
                a2 = fmaf(pre, sW2[(e0 + 2) * 17 + hh], a2);
                a3 = fmaf(pre, sW2[(e0 + 3) * 17 + hh], a3);
            }
            const unsigned ep0 = pk2bf(a0, a1), ep1 = pk2bf(a2, a3);
            #pragma unroll
            for (int bufi = 0; bufi < 2; ++bufi) {
                unsigned short* row = &sA[bufi * MT * ASTR + erow * ASTR];
                *reinterpret_cast<unsigned*>(&row[e0])       = ep0;
                *reinterpret_cast<unsigned*>(&row[e0 + 2])   = ep1;
                *reinterpret_cast<unsigned*>(&row[144 + e0]) = 0u;
                *reinterpret_cast<unsigned*>(&row[144 + e0 + 2]) = 0u;
            }
            // initial h = z[b] (bf16) into buffer 0, cols 16..143: 32 elems/thread
            const unsigned b_idx = (unsigned)gr / 5u;
            const float* zb = z + (size_t)b_idx * 128 + esub * 32;
            unsigned short* hrow = &sA[erow * ASTR + 16 + esub * 32];
            #pragma unroll
            for (int c = 0; c < 2; ++c) {
                const float4 q0 = *reinterpret_cast<const float4*>(zb + c * 16);
                const float4 q1 = *reinterpret_cast<const float4*>(zb + c * 16 + 4);
                const float4 q2 = *reinterpret_cast<const float4*>(zb + c * 16 + 8);
                const float4 q3 = *reinterpret_cast<const float4*>(zb + c * 16 + 12);
                union { u16x8 v; unsigned u32[4]; } w0, w1;
                w0.u32[0] = pk2bf(q0.x, q0.y); w0.u32[1] = pk2bf(q0.z, q0.w);
                w0.u32[2] = pk2bf(q1.x, q1.y); w0.u32[3] = pk2bf(q1.z, q1.w);
                w1.u32[0] = pk2bf(q2.x, q2.y); w1.u32[1] = pk2bf(q2.z, q2.w);
                w1.u32[2] = pk2bf(q3.x, q3.y); w1.u32[3] = pk2bf(q3.z, q3.w);
                *reinterpret_cast<u16x8*>(hrow + c * 16)     = w0.v;
                *reinterpret_cast<u16x8*>(hrow + c * 16 + 8) = w1.v;
            }
        }

        float cst[32];
        #pragma unroll
        for (int e = 0; e < 32; ++e) cst[e] = 0.0f;

        #pragma unroll
        for (int s = 0; s < HN; ++s) {
            const int cur = s & 1;          // compile-time after unroll
            const int nxt = cur ^ 1;
            __syncthreads();   // staging / previous-step h writes visible

            const unsigned short* rb = rbB[cur];
            unsigned short*       wb = wbB[nxt];

            // ---- 8 m-tiles: MFMA(mt) with af ping-pong prefetch; PW(mt-1)
            //      issued in MFMA(mt)'s window via acc bank ping-pong ----
            f32x4 acc[2][4];
            bf16x8 af[2][5];
            #pragma unroll
            for (int kt = 0; kt < 5; ++kt)
                af[0][kt] = *reinterpret_cast<const bf16x8*>(rb + kt * 32);

            #pragma unroll
            for (int mt = 0; mt < 8; ++mt) {
                const int pb = mt & 1;
                #pragma unroll
                for (int t = 0; t < 4; ++t)
                    acc[pb][t] = splat4(biasv[t]);
                if (mt < 7) {
                    #pragma unroll
                    for (int kt = 0; kt < 5; ++kt)
                        af[pb ^ 1][kt] = *reinterpret_cast<const bf16x8*>(
                            rb + (mt + 1) * 16 * ASTR + kt * 32);
                }
                #pragma unroll
                for (int kt = 0; kt < 5; ++kt)
                    #pragma unroll
                    for (int t = 0; t < 4; ++t)
                        acc[pb][t] = __builtin_amdgcn_mfma_f32_16x16x32_bf16(
                            af[pb][kt], Bf[t][kt], acc[pb][t], 0, 0, 0);
                // pointwise of previous m-tile (independent of this mt's MFMAs)
                if (mt == 1) PW_MT(0, 0, wb);
                else if (mt == 2) PW_MT(1, 1, wb);
                else if (mt == 3) PW_MT(0, 2, wb);
                else if (mt == 4) PW_MT(1, 3, wb);
                else if (mt == 5) PW_MT(0, 4, wb);
                else if (mt == 6) PW_MT(1, 5, wb);
                else if (mt == 7) PW_MT(0, 6, wb);
            }
            PW_MT(1, 7, wb);
        }

        __syncthreads();   // final h (buffer 1) complete

        // -------- epilogue: heads; 4 threads/row, 32 l each --------
        {
            const int row = tid >> 2;    // 0..127
            const int j   = tid & 3;     // 0..3
            const unsigned short* hrow = &sA[1 * MT * ASTR + row * ASTR + 16 + j * 32];
            float p = 0.f, q0 = 0.f, q1 = 0.f, q2 = 0.f;
            #pragma unroll
            for (int c = 0; c < 4; ++c) {
                const u16x8 hv8 = *reinterpret_cast<const u16x8*>(hrow + c * 8);
                #pragma unroll
                for (int u = 0; u < 8; ++u) {
                    const int l = j * 32 + c * 8 + u;
                    const float hv = bf2f(hv8[u]);
                    p  = fmaf(hv, sWp[l], p);
                    q0 = fmaf(hv, sWr[l], q0);
                    q1 = fmaf(hv, sWr[128 + l], q1);
                    q2 = fmaf(hv, sWr[256 + l], q2);
                }
            }
            #pragma unroll
            for (int m = 1; m < 4; m <<= 1) {
                p  += __shfl_xor(p,  m, 64);
                q0 += __shfl_xor(q0, m, 64);
                q1 += __shfl_xor(q1, m, 64);
                q2 += __shfl_xor(q2, m, 64);
            }
            if (j == 0) {
                const int gr = r0g + row;
                const float prog  = p + bpv;
                const float rr0 = q0 + br0, rr1 = q1 + br1, rr2 = q2 + br2;
                const float rmean = (rr0 + rr1 + rr2) * (1.0f / 3.0f);
                const float s0 = sigm(rr0), s1 = sigm(rr1), s2 = sigm(rr2);
                const float sm = (s0 + s1 + s2) * (1.0f / 3.0f);
                const float d0 = s0 - sm, d1 = s1 - sm, d2 = s2 - sm;
                const float unc = (d0 * d0 + d1 * d1 + d2 * d2) * 0.5f;   // ddof=1
                out[gr]          = rmean;
                out[BK + gr]     = prog;
                out[2 * BK + gr] = unc;
                out[3 * BK + gr] = rr0;
                out[4 * BK + gr] = rr1;
                out[5 * BK + gr] = rr2;
            }
        }
        // next-tile staging writes emb/pad cols (both bufs) + buf0 h (z);
        // epilogue reads buf1 h-cols — disjoint; step-0 barrier orders the rest.
    }
}

extern "C" void kernel_launch(void* const* d_in, const int* in_sizes, int n_in,
                              void* d_out, int out_size, void* d_ws, size_t ws_size,
                              hipStream_t stream) {
    const float* z       = (const float*)d_in[0];
    const float* anchors = (const float*)d_in[1];
    const float* W1      = (const float*)d_in[2];
    const float* b1      = (const float*)d_in[3];
    const float* W2      = (const float*)d_in[4];
    const float* b2      = (const float*)d_in[5];
    const float* Wih     = (const float*)d_in[6];
    const float* Whh     = (const float*)d_in[7];
    const float* bih     = (const float*)d_in[8];
    const float* bhh     = (const float*)d_in[9];
    const float* Wp      = (const float*)d_in[10];
    const float* bp      = (const float*)d_in[11];
    const float* Wr      = (const float*)d_in[12];
    const float* br      = (const float*)d_in[13];

    hipLaunchKernelGGL(wahead_kernel, dim3(WGS), dim3(THREADS), 0, stream,
                       z, anchors, W1, b1, W2, b2, Wih, Whh, bih, bhh,
                       Wp, bp, Wr, br, (float*)d_out);
}